// Round 1
// baseline (995.559 us; speedup 1.0000x reference)
//
#include <hip/hip_runtime.h>
#include <math.h>

#define BB 4
#define NN 4096
#define KK 20

__device__ __forceinline__ float lrelu(float x){ return x > 0.f ? x : 0.2f*x; }

// order-preserving f32 -> u32 (monotone), and inverse
__device__ __forceinline__ unsigned ordf(float v){
  unsigned u = __float_as_uint(v);
  return u ^ (((unsigned)((int)u >> 31)) | 0x80000000u);
}
__device__ __forceinline__ float iordf(unsigned o){
  unsigned u = (o & 0x80000000u) ? (o ^ 0x80000000u) : ~o;
  return __uint_as_float(u);
}

// ---------------------------------------------------------------------------
// Exact top-20 of 4096 keys per wave. dl = this wave's 4096 ord-values in LDS,
// element j stored at (j>>6)*64 + ((j&63)^(j>>6))  (XOR swizzle: both own-scan
// and cooperative rescan are conflict-free). Selection order: desc value,
// asc index (matches lax.top_k). Returns lane r's selection for r<20.
// bestord/bestj: lane's max over its own slots (j%64==lane), computed by caller.
__device__ __forceinline__ int topk20(const unsigned* dl, int lane, unsigned bestord, int bestj){
  int my = 0;
  for (int r = 0; r < 20; ++r){
    unsigned long long k = ((unsigned long long)bestord << 12) | (unsigned)(4095 - bestj);
    #pragma unroll
    for (int off = 32; off; off >>= 1){
      unsigned long long o = __shfl_xor(k, off);
      if (o > k) k = o;
    }
    int selj = 4095 - (int)(k & 0xFFFull);
    if (lane == r) my = selj;
    int wl = selj & 63;
    // cooperative rescan of winner lane's 64 slots (lane handles slot s=lane)
    unsigned od2 = dl[(lane << 6) + (wl ^ lane)];
    int j2 = (lane << 6) + wl;
    unsigned long long k2 = ((unsigned long long)od2 << 12) | (unsigned)(4095 - j2);
    if (k2 >= k) k2 = 0ull;            // exclude already-selected (keys >= current)
    #pragma unroll
    for (int off = 32; off; off >>= 1){
      unsigned long long o = __shfl_xor(k2, off);
      if (o > k2) k2 = o;
    }
    if (lane == wl){ bestord = (unsigned)(k2 >> 12); bestj = 4095 - (int)(k2 & 0xFFFull); }
  }
  return my;
}

// ---------------------------------------------------------------------------
// kNN on xyz (C=3). One wave per row. dist kept in LDS (ord u32, swizzled).
__global__ __launch_bounds__(256) void knn_xyz(const float* __restrict__ xyz, int* __restrict__ idx_out){
  __shared__ unsigned dist[4][4096];   // 64KB
  int tid = threadIdx.x, wv = tid >> 6, lane = tid & 63;
  int row = blockIdx.x * 4 + wv;
  int b = row >> 12, i = row & 4095;
  const float* xb = xyz + (size_t)b * NN * 3;
  float xi0 = xb[i*3+0], xi1 = xb[i*3+1], xi2 = xb[i*3+2];
  float xxi = xi0*xi0 + xi1*xi1 + xi2*xi2;
  unsigned bestord = 0; int bestj = 0;
  for (int s = 0; s < 64; ++s){
    int j = s*64 + lane;
    float a0 = xb[j*3+0], a1 = xb[j*3+1], a2 = xb[j*3+2];
    float inner = xi0*a0 + xi1*a1 + xi2*a2;
    float xxj = a0*a0 + a1*a1 + a2*a2;
    float d = -xxi + 2.f*inner - xxj;     // reference formula order
    unsigned od = ordf(d);
    dist[wv][s*64 + (lane ^ s)] = od;
    if (od > bestord){ bestord = od; bestj = j; }
  }
  __syncthreads();
  int my = topk20(&dist[wv][0], lane, bestord, bestj);
  if (lane < 20) idx_out[(size_t)row*20 + lane] = my;
}

// top-20 per row from a precomputed ord-dist matrix [4096][4096]
__global__ __launch_bounds__(256) void topk_rows(const unsigned* __restrict__ dg, int* __restrict__ idx_out){
  __shared__ unsigned dist[4][4096];
  int tid = threadIdx.x, wv = tid >> 6, lane = tid & 63;
  int i = blockIdx.x * 4 + wv;
  const unsigned* drow = dg + (size_t)i * 4096;
  unsigned bestord = 0; int bestj = 0;
  for (int s = 0; s < 64; ++s){
    unsigned od = drow[s*64 + lane];
    dist[wv][s*64 + (lane ^ s)] = od;
    if (od > bestord){ bestord = od; bestj = s*64 + lane; }
  }
  __syncthreads();
  int my = topk20(&dist[wv][0], lane, bestord, bestj);
  if (lane < 20) idx_out[(size_t)i*20 + lane] = my;
}

// ---------------------------------------------------------------------------
// Gram + negative-sq-distance (ord u32) for one batch: dg[i][j] = ord(2*G - xx_i - xx_j)
// x1 = xper rows (stride 128, first 64 cols). 128x128 block tile, 8x8 per lane.
__global__ __launch_bounds__(256) void gram_dist(const float* __restrict__ x1, const float* __restrict__ xx,
                                                 unsigned* __restrict__ dg){
  int it = blockIdx.y, jt = blockIdx.x;
  if (jt < it) return;                  // symmetry: mirror-write instead
  __shared__ __align__(16) float Atl[128*64];
  __shared__ __align__(16) float Btl[128*64];
  int tid = threadIdx.x;
  for (int q = 0; q < 8; ++q){
    int e4 = q*256 + tid;               // 2048 float4 per tile
    int r = e4 >> 4, c4 = e4 & 15;
    int cs = (c4 ^ ((r >> 3) & 7)) << 2;
    *(float4*)&Atl[r*64 + cs] = *(const float4*)&x1[(size_t)(it*128 + r)*128 + c4*4];
    *(float4*)&Btl[r*64 + cs] = *(const float4*)&x1[(size_t)(jt*128 + r)*128 + c4*4];
  }
  __syncthreads();
  int wv = tid >> 6, lane = tid & 63;
  int wy = wv >> 1, wx = wv & 1, ly = lane >> 3, lx = lane & 7;
  int ib = wy*64 + ly*8, jb = wx*64 + lx*8;
  float acc[8][8] = {};
  for (int k4 = 0; k4 < 16; ++k4){
    float a[8][4], bb[8][4];
    #pragma unroll
    for (int p = 0; p < 8; ++p){
      float4 v = *(const float4*)&Atl[(ib + p)*64 + ((k4 ^ ly) << 2)];
      a[p][0]=v.x; a[p][1]=v.y; a[p][2]=v.z; a[p][3]=v.w;
      float4 u = *(const float4*)&Btl[(jb + p)*64 + ((k4 ^ lx) << 2)];
      bb[p][0]=u.x; bb[p][1]=u.y; bb[p][2]=u.z; bb[p][3]=u.w;
    }
    #pragma unroll
    for (int kk = 0; kk < 4; ++kk)
      #pragma unroll
      for (int p = 0; p < 8; ++p)
        #pragma unroll
        for (int q = 0; q < 8; ++q)
          acc[p][q] += a[p][kk] * bb[q][kk];
  }
  float xxi[8], xxj[8];
  #pragma unroll
  for (int p = 0; p < 8; ++p){ xxi[p] = xx[it*128 + ib + p]; xxj[p] = xx[jt*128 + jb + p]; }
  #pragma unroll
  for (int p = 0; p < 8; ++p){
    unsigned ow[8];
    #pragma unroll
    for (int q = 0; q < 8; ++q){ float d = -xxi[p] + 2.f*acc[p][q] - xxj[q]; ow[q] = ordf(d); }
    size_t o = (size_t)(it*128 + ib + p)*4096 + jt*128 + jb;
    *(uint4*)&dg[o]   = make_uint4(ow[0],ow[1],ow[2],ow[3]);
    *(uint4*)&dg[o+4] = make_uint4(ow[4],ow[5],ow[6],ow[7]);
  }
  if (jt > it){
    #pragma unroll
    for (int q = 0; q < 8; ++q){
      unsigned ow[8];
      #pragma unroll
      for (int p = 0; p < 8; ++p){ float d = -xxi[p] + 2.f*acc[p][q] - xxj[q]; ow[p] = ordf(d); }
      size_t o = (size_t)(jt*128 + jb + q)*4096 + it*128 + ib;
      *(uint4*)&dg[o]   = make_uint4(ow[0],ow[1],ow[2],ow[3]);
      *(uint4*)&dg[o+4] = make_uint4(ow[4],ow[5],ow[6],ow[7]);
    }
  }
}

__global__ __launch_bounds__(256) void row_norms(const float* __restrict__ xper, float* __restrict__ xx){
  int wv = threadIdx.x >> 6, lane = threadIdx.x & 63;
  int row = blockIdx.x * 4 + wv;
  float v = xper[(size_t)row*128 + lane];   // x1 part (cols 0..63)
  float s = v*v;
  #pragma unroll
  for (int off = 32; off; off >>= 1) s += __shfl_xor(s, off);
  if (lane == 0) xx[row] = s;
}

// ---------------------------------------------------------------------------
// conv1a: z[row][o] = sum_c f(row)[c]*w1a[o][c], f = [xj-xi | xi], C=6.
// Also per-block channel partials of (z, z^2).
__global__ __launch_bounds__(256) void conv1a(const float* __restrict__ xyz, const int* __restrict__ idx,
                                              const float* __restrict__ w1a, float* __restrict__ out,
                                              float* __restrict__ part1, float* __restrict__ part2){
  int tid = threadIdx.x, wv = tid >> 6, lane = tid & 63;
  float w[6];
  #pragma unroll
  for (int c = 0; c < 6; ++c) w[c] = w1a[lane*6 + c];
  float s1 = 0.f, s2 = 0.f;
  int base = blockIdx.x*64 + wv*16;
  for (int r = 0; r < 16; ++r){
    int row = base + r;
    int bn = row / 20; int b = bn >> 12;
    int j = idx[row];
    const float* xb = xyz + (size_t)b * NN * 3;
    const float* xi = xb + (size_t)(bn & 4095) * 3;
    const float* xj = xb + (size_t)j * 3;
    float i0 = xi[0], i1 = xi[1], i2 = xi[2];
    float z = w[0]*(xj[0]-i0) + w[1]*(xj[1]-i1) + w[2]*(xj[2]-i2) + w[3]*i0 + w[4]*i1 + w[5]*i2;
    out[(size_t)row*64 + lane] = z;
    s1 += z; s2 += z*z;
  }
  __shared__ float red[2][4][64];
  red[0][wv][lane] = s1; red[1][wv][lane] = s2;
  __syncthreads();
  if (tid < 64)
    part1[(size_t)blockIdx.x*64 + tid] = red[0][0][tid]+red[0][1][tid]+red[0][2][tid]+red[0][3][tid];
  else if (tid < 128){
    int c = tid - 64;
    part2[(size_t)blockIdx.x*64 + c] = red[1][0][c]+red[1][1][c]+red[1][2][c]+red[1][3][c];
  }
}

// ---------------------------------------------------------------------------
// Generic rows-GEMM: out[row][o] = oscale * sum_c feat(row)[c] * W[o][c]
// VAR 0: feat = A rows (stride CIN).  VAR 1: feat = lrelu(bn(A rows)) via statsIn.
// VAR 2: feat = graph_feature gather from xper (CIN=128): [xj-xi | xi], j=idx[row].
// Block: 128 threads, 128 rows x 64 out-channels; per-lane 8x8 acc; k in chunks of 32.
// Optional per-block channel partials (z, z^2) for BN stats.
template<int CIN, int VAR>
__global__ __launch_bounds__(128) void gemm_rows(const float* A, const float* __restrict__ W,
                                                 float* out, int ostride,
                                                 float* __restrict__ part1, float* __restrict__ part2,
                                                 const float* __restrict__ statsIn,
                                                 const int* __restrict__ idx, float oscale){
  __shared__ __align__(16) float Al[128*32];
  __shared__ __align__(16) float Bl[64*32];
  __shared__ float pl[2][2][8][64];
  int tid = threadIdx.x;
  int wv = tid >> 6, lane = tid & 63;
  int ly = lane >> 3, lx = lane & 7;
  int rowbase = blockIdx.x * 128;
  int chb = blockIdx.y;
  float acc[8][8] = {};
  const int NKC = CIN / 32;
  for (int kc = 0; kc < NKC; ++kc){
    __syncthreads();
    // stage A: 128 rows x 32 k  (1024 float4, 8 per thread)
    for (int q8 = 0; q8 < 8; ++q8){
      int e4 = q8*128 + tid;
      int r = e4 >> 3, c4 = e4 & 7;
      int cg = kc*32 + c4*4;
      float4 v;
      if (VAR == 2){
        int row = rowbase + r;
        int bn = row / 20; int b = bn >> 12;
        int j = idx[row];
        const float* xi = A + (size_t)bn * 128;
        const float* xj = A + ((size_t)(b << 12) + j) * 128;
        if (cg < 64){
          float4 a1 = *(const float4*)&xj[cg];
          float4 a0 = *(const float4*)&xi[cg];
          v = make_float4(a1.x-a0.x, a1.y-a0.y, a1.z-a0.z, a1.w-a0.w);
        } else {
          v = *(const float4*)&xi[cg - 64];
        }
      } else {
        v = *(const float4*)&A[(size_t)(rowbase + r)*CIN + cg];
        if (VAR == 1){
          float4 m4 = *(const float4*)&statsIn[cg];
          float4 r4 = *(const float4*)&statsIn[CIN + cg];
          v.x = lrelu((v.x - m4.x)*r4.x); v.y = lrelu((v.y - m4.y)*r4.y);
          v.z = lrelu((v.z - m4.z)*r4.z); v.w = lrelu((v.w - m4.w)*r4.w);
        }
      }
      *(float4*)&Al[r*32 + ((c4 ^ ((r >> 3) & 7)) << 2)] = v;
    }
    // stage B: 64 ch x 32 k  (512 float4, 4 per thread)
    for (int q8 = 0; q8 < 4; ++q8){
      int e4 = q8*128 + tid;
      int ch = e4 >> 3, c4 = e4 & 7;
      float4 v = *(const float4*)&W[(size_t)(chb*64 + ch)*CIN + kc*32 + c4*4];
      *(float4*)&Bl[ch*32 + ((c4 ^ ((ch >> 3) & 7)) << 2)] = v;
    }
    __syncthreads();
    for (int k4 = 0; k4 < 8; ++k4){
      float a[8][4], bb[8][4];
      #pragma unroll
      for (int p = 0; p < 8; ++p){
        int r = wv*64 + ly*8 + p;                 // (r>>3)&7 == ly
        float4 v = *(const float4*)&Al[r*32 + ((k4 ^ ly) << 2)];
        a[p][0]=v.x; a[p][1]=v.y; a[p][2]=v.z; a[p][3]=v.w;
        int ch = lx*8 + p;                        // (ch>>3)&7 == lx
        float4 u = *(const float4*)&Bl[ch*32 + ((k4 ^ lx) << 2)];
        bb[p][0]=u.x; bb[p][1]=u.y; bb[p][2]=u.z; bb[p][3]=u.w;
      }
      #pragma unroll
      for (int kk = 0; kk < 4; ++kk)
        #pragma unroll
        for (int p = 0; p < 8; ++p)
          #pragma unroll
          for (int q = 0; q < 8; ++q)
            acc[p][q] += a[p][kk] * bb[q][kk];
    }
  }
  // write out (rows p, channels lx*8..lx*8+7)
  #pragma unroll
  for (int p = 0; p < 8; ++p){
    int row = rowbase + wv*64 + ly*8 + p;
    float4 o0 = make_float4(acc[p][0]*oscale, acc[p][1]*oscale, acc[p][2]*oscale, acc[p][3]*oscale);
    float4 o1 = make_float4(acc[p][4]*oscale, acc[p][5]*oscale, acc[p][6]*oscale, acc[p][7]*oscale);
    *(float4*)&out[(size_t)row*ostride + chb*64 + lx*8]     = o0;
    *(float4*)&out[(size_t)row*ostride + chb*64 + lx*8 + 4] = o1;
  }
  if (part1){
    #pragma unroll
    for (int q = 0; q < 8; ++q){
      float t1 = 0.f, t2 = 0.f;
      #pragma unroll
      for (int p = 0; p < 8; ++p){ float v = acc[p][q]; t1 += v; t2 += v*v; }
      pl[0][wv][ly][lx*8 + q] = t1;
      pl[1][wv][ly][lx*8 + q] = t2;
    }
    __syncthreads();
    int nchTot = gridDim.y * 64;
    if (tid < 64){
      float s = 0.f;
      #pragma unroll
      for (int w2 = 0; w2 < 2; ++w2)
        #pragma unroll
        for (int l2 = 0; l2 < 8; ++l2) s += pl[0][w2][l2][tid];
      part1[(size_t)blockIdx.x*nchTot + chb*64 + tid] = s;
    } else {
      int c = tid - 64;
      float s = 0.f;
      #pragma unroll
      for (int w2 = 0; w2 < 2; ++w2)
        #pragma unroll
        for (int l2 = 0; l2 < 8; ++l2) s += pl[1][w2][l2][c];
      part2[(size_t)blockIdx.x*nchTot + chb*64 + c] = s;
    }
  }
}

// deterministic partial -> (mean, rstd) per channel
__global__ __launch_bounds__(256) void stats_reduce(const float* __restrict__ p1, const float* __restrict__ p2,
                                                    float* __restrict__ statsOut, int nblk, int nch, float count){
  int ch = blockIdx.x, tid = threadIdx.x;
  float s1 = 0.f, s2 = 0.f;
  for (int i = tid; i < nblk; i += 256){ s1 += p1[(size_t)i*nch + ch]; s2 += p2[(size_t)i*nch + ch]; }
  __shared__ float r1[256], r2[256];
  r1[tid] = s1; r2[tid] = s2;
  __syncthreads();
  for (int off = 128; off; off >>= 1){
    if (tid < off){ r1[tid] += r1[tid+off]; r2[tid] += r2[tid+off]; }
    __syncthreads();
  }
  if (tid == 0){
    float m = r1[0] / count;
    float var = r2[0] / count - m*m;
    if (var < 0.f) var = 0.f;
    statsOut[ch] = m;
    statsOut[nch + ch] = rsqrtf(var + 1e-5f);
  }
}

// bn+lrelu then max over k=20 -> xper[:, off..off+63]
__global__ __launch_bounds__(256) void colmax(const float* __restrict__ buf, const float* __restrict__ st,
                                              float* __restrict__ xper, int off){
  int wv = threadIdx.x >> 6, lane = threadIdx.x & 63;
  int bn = blockIdx.x*4 + wv;
  float m = st[lane], rs = st[64 + lane];
  float mx = -INFINITY;
  for (int k = 0; k < 20; ++k){
    float z = buf[((size_t)bn*20 + k)*64 + lane];
    mx = fmaxf(mx, lrelu((z - m)*rs));
  }
  xper[(size_t)bn*128 + off + lane] = mx;
}

// bn+lrelu then max over n (atomicMax on ord-u32; order-independent => deterministic)
__global__ __launch_bounds__(256) void g_final(const float* __restrict__ z3, const float* __restrict__ st,
                                               unsigned* __restrict__ xglob){
  int t = threadIdx.x, zid = blockIdx.x;
  int b = zid >> 6, og = (zid >> 4) & 3, nc = zid & 15;
  int o = og*256 + t;
  float m = st[o], rs = st[1024 + o];
  float mx = -INFINITY;
  for (int r = 0; r < 256; ++r){
    float z = z3[((size_t)(b*4096 + nc*256 + r))*1024 + o];
    mx = fmaxf(mx, lrelu((z - m)*rs));
  }
  atomicMax(xglob + b*1024 + o, ordf(mx));
}

__global__ __launch_bounds__(256) void head(const unsigned* __restrict__ xglob,
                                            const float* __restrict__ mu_w, const float* __restrict__ mu_b,
                                            const float* __restrict__ var_w, const float* __restrict__ var_b,
                                            const float* __restrict__ eps_z, float* __restrict__ dout,
                                            float* __restrict__ zv){
  __shared__ __align__(16) float xg[1024];
  int b = blockIdx.x, t = threadIdx.x;
  for (int q = 0; q < 4; ++q) xg[q*256 + t] = iordf(xglob[b*1024 + q*256 + t]);
  __syncthreads();
  if (t < 128){
    float s1 = 0.f, s2 = 0.f;
    for (int c = 0; c < 1024; c += 4){
      float4 xv = *(const float4*)&xg[c];
      float4 wa = *(const float4*)&mu_w[(size_t)t*1024 + c];
      float4 wb = *(const float4*)&var_w[(size_t)t*1024 + c];
      s1 += wa.x*xv.x + wa.y*xv.y + wa.z*xv.z + wa.w*xv.w;
      s2 += wb.x*xv.x + wb.y*xv.y + wb.z*xv.z + wb.w*xv.w;
    }
    float mu = s1 + mu_b[t];
    float lv = s2 + var_b[t];
    dout[458816 + b*128 + t] = mu;
    dout[459328 + b*128 + t] = lv;
    zv[b*128 + t] = eps_z[b*128 + t] * expf(0.5f*lv) + mu;
  }
}

// cuboid MLP + Para_pred per (b,m): xc(192) -> h1(256) -> x_cuboid(128) -> {Km, quat->rot, trans, exist}
__global__ __launch_bounds__(256) void cuboid(const float* __restrict__ zv, const float* __restrict__ enc_w,
                                              const float* __restrict__ w1, const float* __restrict__ w2,
                                              const float* __restrict__ rot_w, const float* __restrict__ rot_b,
                                              const float* __restrict__ trans_w, const float* __restrict__ trans_b,
                                              const float* __restrict__ ext_w1, const float* __restrict__ ext_b1,
                                              const float* __restrict__ ext_w2, const float* __restrict__ ext_b2,
                                              const float* __restrict__ k_w, float* __restrict__ Km,
                                              float* __restrict__ rot, float* __restrict__ trs,
                                              float* __restrict__ dout){
  int bm = blockIdx.x; int b = bm >> 4, m = bm & 15; int t = threadIdx.x;
  __shared__ __align__(16) float xc[192];
  __shared__ __align__(16) float h1[256];
  __shared__ __align__(16) float xcu[128];
  __shared__ float qv[4]; __shared__ float ev[30];
  if (t < 192) xc[t] = (t < 128) ? zv[b*128 + t] : lrelu(enc_w[(t-128)*16 + m]);
  __syncthreads();
  {
    float s = 0.f; const float* wr = w1 + (size_t)t*192;
    for (int c = 0; c < 192; c += 4){
      float4 w4 = *(const float4*)&wr[c]; float4 x4 = *(const float4*)&xc[c];
      s += w4.x*x4.x + w4.y*x4.y + w4.z*x4.z + w4.w*x4.w;
    }
    h1[t] = lrelu(s);
  }
  __syncthreads();
  if (t < 128){
    float s = 0.f; const float* wr = w2 + (size_t)t*256;
    for (int c = 0; c < 256; c += 4){
      float4 w4 = *(const float4*)&wr[c]; float4 x4 = *(const float4*)&h1[c];
      s += w4.x*x4.x + w4.y*x4.y + w4.z*x4.z + w4.w*x4.w;
    }
    xcu[t] = lrelu(s);
  }
  __syncthreads();
  if (t < 64){
    float s = 0.f;
    for (int c = 0; c < 128; ++c) s += xcu[c]*k_w[(size_t)t*128 + c];
    Km[(size_t)(b*16 + m)*64 + t] = s;
  } else if (t < 68){
    int o = t - 64; float s = rot_b[o];
    for (int c = 0; c < 128; ++c) s += xcu[c]*rot_w[(size_t)o*128 + c];
    qv[o] = s;
  } else if (t < 71){
    int o = t - 68; float s = trans_b[o];
    for (int c = 0; c < 128; ++c) s += xcu[c]*trans_w[(size_t)o*128 + c];
    trs[(size_t)(b*16 + m)*3 + o] = tanhf(s);
  } else if (t < 101){
    int o = t - 71; float s = ext_b1[o];
    for (int c = 0; c < 128; ++c) s += xcu[c]*ext_w1[(size_t)o*128 + c];
    ev[o] = lrelu(s);
  }
  __syncthreads();
  if (t == 0){
    float w = qv[0], x = qv[1], y = qv[2], z = qv[3];
    float nrm = sqrtf(w*w + x*x + y*y + z*z);
    float inv = 1.f / fmaxf(nrm, 1e-12f);
    w *= inv; x *= inv; y *= inv; z *= inv;
    float xx2 = x*x, yy = y*y, zz = z*z;
    float* r = rot + (size_t)(b*16 + m)*9;
    r[0] = 1.f - 2.f*(yy + zz); r[1] = 2.f*(x*y - w*z); r[2] = 2.f*(x*z + w*y);
    r[3] = 2.f*(x*y + w*z); r[4] = 1.f - 2.f*(xx2 + zz); r[5] = 2.f*(y*z - w*x);
    r[6] = 2.f*(x*z - w*y); r[7] = 2.f*(y*z + w*x); r[8] = 1.f - 2.f*(xx2 + yy);
  }
  if (t == 1){
    float s = ext_b2[0];
    for (int o = 0; o < 30; ++o) s += ev[o]*ext_w2[o];
    dout[458752 + b*16 + m] = s;
  }
}

// attention epilogue: scores, softmax over m, assign / assign_rotate / assign_trans
__global__ __launch_bounds__(256) void attn(const float* __restrict__ Qbuf, const float* __restrict__ Km,
                                            const float* __restrict__ rot, const float* __restrict__ trs,
                                            float* __restrict__ dout){
  __shared__ float kml[16*64];
  __shared__ float rl[144], tl[48];
  __shared__ float Ql[4][64];
  __shared__ float al[4][16];
  int tid = threadIdx.x, wv = tid >> 6, lane = tid & 63;
  int bn0 = blockIdx.x*4; int b = bn0 >> 12;
  for (int e = tid; e < 1024; e += 256){
    int m = e >> 6, d = e & 63;
    kml[m*64 + (d ^ ((m & 15) << 2))] = Km[(size_t)b*1024 + e];
  }
  if (tid < 144) rl[tid] = rot[(size_t)b*144 + tid];
  if (tid < 48)  tl[tid] = trs[(size_t)b*48 + tid];
  __syncthreads();
  int bn = bn0 + wv;
  Ql[wv][lane] = Qbuf[(size_t)bn*64 + lane];
  if (lane < 16){
    float sc = 0.f;
    for (int d = 0; d < 64; ++d) sc += Ql[wv][d] * kml[lane*64 + (d ^ ((lane & 15) << 2))];
    float mx = sc;
    #pragma unroll
    for (int off = 8; off; off >>= 1) mx = fmaxf(mx, __shfl_xor(mx, off));
    float e = expf(sc - mx);
    float sm = e;
    #pragma unroll
    for (int off = 8; off; off >>= 1) sm += __shfl_xor(sm, off);
    float a = e / sm;
    dout[(size_t)bn*16 + lane] = a;           // assign
    al[wv][lane] = a;
  }
  if (lane < 9){
    float s = 0.f;
    for (int m = 0; m < 16; ++m) s += al[wv][m] * rl[m*9 + lane];
    dout[262144 + (size_t)bn*9 + lane] = s;   // assign_rotate
  }
  if (lane >= 16 && lane < 19){
    int d = lane - 16;
    float s = 0.f;
    for (int m = 0; m < 16; ++m) s += al[wv][m] * tl[m*3 + d];
    dout[409600 + (size_t)bn*3 + d] = s;      // assign_trans
  }
}

// ---------------------------------------------------------------------------
extern "C" void kernel_launch(void* const* d_in, const int* in_sizes, int n_in,
                              void* d_out, int out_size, void* d_ws, size_t ws_size,
                              hipStream_t stream){
  (void)in_sizes; (void)n_in; (void)out_size; (void)ws_size;
  const float* xyz     = (const float*)d_in[0];
  const float* eps_z   = (const float*)d_in[2];
  const float* w1a     = (const float*)d_in[3];
  const float* w1b     = (const float*)d_in[4];
  const float* w2a     = (const float*)d_in[5];
  const float* w2b     = (const float*)d_in[6];
  const float* w3      = (const float*)d_in[7];
  const float* mu_w    = (const float*)d_in[8];
  const float* mu_b    = (const float*)d_in[9];
  const float* var_w   = (const float*)d_in[10];
  const float* var_b   = (const float*)d_in[11];
  const float* enc_w   = (const float*)d_in[12];
  const float* cw1     = (const float*)d_in[13];
  const float* cw2     = (const float*)d_in[14];
  const float* q_w     = (const float*)d_in[15];
  const float* k_w     = (const float*)d_in[16];
  const float* rot_w   = (const float*)d_in[19];
  const float* rot_b   = (const float*)d_in[20];
  const float* trans_w = (const float*)d_in[21];
  const float* trans_b = (const float*)d_in[22];
  const float* ext_w1  = (const float*)d_in[23];
  const float* ext_b1  = (const float*)d_in[24];
  const float* ext_w2  = (const float*)d_in[25];
  const float* ext_b2  = (const float*)d_in[26];
  float* dout = (float*)d_out;

  char* wsb = (char*)d_ws;
  size_t off = 0;
  float* buf   = (float*)(wsb + off); off += 83886080;      // [B,N,K,64] f32; reused for dist (64MB) and z3 (64MB)
  int*   idx0  = (int*)(wsb + off);   off += 1310720;
  int*   idx1  = (int*)(wsb + off);   off += 1310720;
  float* xper  = (float*)(wsb + off); off += 8388608;       // [B,N,128] = [x1|x2]
  float* xx    = (float*)(wsb + off); off += 65536;
  float* part1 = (float*)(wsb + off); off += 4194304;       // 1M floats; reused as Qbuf
  float* part2 = (float*)(wsb + off); off += 4194304;
  float* st1a  = (float*)(wsb + off); off += 512;
  float* st1b  = (float*)(wsb + off); off += 512;
  float* st2a  = (float*)(wsb + off); off += 512;
  float* st2b  = (float*)(wsb + off); off += 512;
  float* st3   = (float*)(wsb + off); off += 8192;
  unsigned* xglob = (unsigned*)(wsb + off); off += 16384;
  float* zv    = (float*)(wsb + off); off += 2048;
  float* Kmb   = (float*)(wsb + off); off += 16384;
  float* rotb  = (float*)(wsb + off); off += 2304;
  float* trsb  = (float*)(wsb + off); off += 768;

  // --- Feature_extract, block 1 ---
  knn_xyz<<<4096, 256, 0, stream>>>(xyz, idx0);
  conv1a<<<5120, 256, 0, stream>>>(xyz, idx0, w1a, buf, part1, part2);
  stats_reduce<<<64, 256, 0, stream>>>(part1, part2, st1a, 5120, 64, 327680.f);
  gemm_rows<64,1><<<dim3(2560,1), 128, 0, stream>>>(buf, w1b, buf, 64, part1, part2, st1a, nullptr, 1.f);
  stats_reduce<<<64, 256, 0, stream>>>(part1, part2, st1b, 2560, 64, 327680.f);
  colmax<<<4096, 256, 0, stream>>>(buf, st1b, xper, 0);     // x1

  // --- knn on x1 (Gram -> ord-dist -> topk), per batch, dist reuses buf ---
  row_norms<<<4096, 256, 0, stream>>>(xper, xx);
  for (int b = 0; b < 4; ++b){
    gram_dist<<<dim3(32,32), 256, 0, stream>>>(xper + (size_t)b*NN*128, xx + (size_t)b*NN, (unsigned*)buf);
    topk_rows<<<1024, 256, 0, stream>>>((unsigned*)buf, idx1 + (size_t)b*NN*KK);
  }

  // --- Feature_extract, block 2 ---
  gemm_rows<128,2><<<dim3(2560,1), 128, 0, stream>>>(xper, w2a, buf, 64, part1, part2, nullptr, idx1, 1.f);
  stats_reduce<<<64, 256, 0, stream>>>(part1, part2, st2a, 2560, 64, 327680.f);
  gemm_rows<64,1><<<dim3(2560,1), 128, 0, stream>>>(buf, w2b, buf, 64, part1, part2, st2a, nullptr, 1.f);
  stats_reduce<<<64, 256, 0, stream>>>(part1, part2, st2b, 2560, 64, 327680.f);
  colmax<<<4096, 256, 0, stream>>>(buf, st2b, xper, 64);    // x2

  // --- global embedding g = lrelu(bn(xper @ w3^T)), x_global = max_n ---
  gemm_rows<128,0><<<dim3(128,16), 128, 0, stream>>>(xper, w3, buf, 1024, part1, part2, nullptr, nullptr, 1.f);
  stats_reduce<<<1024, 256, 0, stream>>>(part1, part2, st3, 128, 1024, 16384.f);
  hipMemsetAsync(xglob, 0, 4096*sizeof(unsigned), stream);  // ord-space minimum
  g_final<<<256, 256, 0, stream>>>(buf, st3, xglob);

  // --- heads ---
  head<<<4, 256, 0, stream>>>(xglob, mu_w, mu_b, var_w, var_b, eps_z, dout, zv);
  cuboid<<<64, 256, 0, stream>>>(zv, enc_w, cw1, cw2, rot_w, rot_b, trans_w, trans_b,
                                 ext_w1, ext_b1, ext_w2, ext_b2, k_w, Kmb, rotb, trsb, dout);
  gemm_rows<128,0><<<dim3(128,1), 128, 0, stream>>>(xper, q_w, part1, 64, nullptr, nullptr, nullptr, nullptr, 0.125f);
  attn<<<4096, 256, 0, stream>>>(part1, Kmb, rotb, trsb, dout);
}

// Round 2
// 899.219 us; speedup vs baseline: 1.1071x; 1.1071x over previous
//
#include <hip/hip_runtime.h>
#include <math.h>

#define BB 4
#define NN 4096
#define KK 20

__device__ __forceinline__ float lrelu(float x){ return x > 0.f ? x : 0.2f*x; }

// order-preserving f32 -> u32 (monotone), and inverse
__device__ __forceinline__ unsigned ordf(float v){
  unsigned u = __float_as_uint(v);
  return u ^ (((unsigned)((int)u >> 31)) | 0x80000000u);
}
__device__ __forceinline__ float iordf(unsigned o){
  unsigned u = (o & 0x80000000u) ? (o ^ 0x80000000u) : ~o;
  return __uint_as_float(u);
}

// ---------------------------------------------------------------------------
// Exact top-20 of 4096 keys per wave, register-resident (no LDS).
// Slot ownership interleaved: lane L owns j = s*64 + L, s in [0,64).
// getv(s,L) returns ord-value of slot j = s*64+L (finite values are > 0).
// Priority = (value desc, global index asc) == lax.top_k tie-break.
// Each lane keeps its top-3 in registers; per round: 32-bit max reduce +
// ballot pick; rare paths (value tie across lanes / lane heap exhausted)
// are wave-uniform branches. Returns lane r's selected j for r<20.
template<typename GetV>
__device__ __forceinline__ int topk20_reg(int lane, GetV getv){
  unsigned b0v = 0u, b1v = 0u, b2v = 0u;
  int b0s = 63, b1s = 63, b2s = 63;
  for (int s = 0; s < 64; ++s){
    unsigned v = getv(s, lane);
    if (v > b0v){ b2v=b1v; b2s=b1s; b1v=b0v; b1s=b0s; b0v=v; b0s=s; }
    else if (v > b1v){ b2v=b1v; b2s=b1s; b1v=v; b1s=s; }
    else if (v > b2v){ b2v=v; b2s=s; }
  }
  unsigned lastv = 0u; int lasts = 0;
  int myj = 0;
  for (int r = 0; r < 20; ++r){
    unsigned m = b0v;
    #pragma unroll
    for (int off = 32; off; off >>= 1){ unsigned o = __shfl_xor(m, off); if (o > m) m = o; }
    unsigned long long msk = __ballot(b0v == m);
    int wl, sels;
    if (__popcll(msk) > 1){
      // value tie across lanes: min (s, lane) wins (lowest global index)
      int kk = (b0v == m) ? ((b0s << 6) | lane) : 0x7fffffff;
      #pragma unroll
      for (int off = 32; off; off >>= 1){ int o = __shfl_xor(kk, off); if (o < kk) kk = o; }
      wl = kk & 63; sels = kk >> 6;
    } else {
      wl = __ffsll(msk) - 1;
      sels = __shfl(b0s, wl);
    }
    if (lane == r) myj = sels*64 + wl;
    bool empty = false;
    if (lane == wl){
      lastv = b0v; lasts = b0s;
      b0v = b1v; b0s = b1s; b1v = b2v; b1s = b2s; b2v = 0u; b2s = 63;
      empty = (b0v == 0u);
    }
    if (__any(empty)){
      // cooperative rebuild of winner lane's chunk (rare)
      unsigned lw = __shfl(lastv, wl); int ls = __shfl(lasts, wl);
      unsigned cv = getv(lane, wl);          // slot s=lane of chunk wl
      bool keep = (cv < lw) || (cv == lw && lane > ls);
      if (!keep) cv = 0u;
      unsigned nv0, nv1, nv2; int ns0, ns1, ns2;
      #pragma unroll
      for (int t = 0; t < 3; ++t){
        unsigned mm = cv;
        #pragma unroll
        for (int off = 32; off; off >>= 1){ unsigned o = __shfl_xor(mm, off); if (o > mm) mm = o; }
        unsigned long long mk = __ballot(cv == mm);
        int src = __ffsll(mk) - 1;           // min s == min lane here
        if (t == 0){ nv0 = mm; ns0 = src; }
        else if (t == 1){ nv1 = mm; ns1 = src; }
        else { nv2 = mm; ns2 = src; }
        if (lane == src) cv = 0u;
      }
      if (lane == wl){ b0v=nv0; b0s=ns0; b1v=nv1; b1s=ns1; b2v=nv2; b2s=ns2; }
    }
  }
  return myj;
}

// ---------------------------------------------------------------------------
// kNN on xyz (C=3). One wave per row, no LDS, distances recomputed on demand.
__global__ __launch_bounds__(256) void knn_xyz(const float* __restrict__ xyz, int* __restrict__ idx_out){
  int tid = threadIdx.x, wv = tid >> 6, lane = tid & 63;
  int row = blockIdx.x * 4 + wv;
  int b = row >> 12, i = row & 4095;
  const float* xb = xyz + (size_t)b * NN * 3;
  float xi0 = xb[i*3+0], xi1 = xb[i*3+1], xi2 = xb[i*3+2];
  float xxi = xi0*xi0 + xi1*xi1 + xi2*xi2;
  auto getv = [=](int s, int L)->unsigned{
    int j = s*64 + L;
    float a0 = xb[j*3+0], a1 = xb[j*3+1], a2 = xb[j*3+2];
    float inner = xi0*a0 + xi1*a1 + xi2*a2;
    float xxj = a0*a0 + a1*a1 + a2*a2;
    return ordf(-xxi + 2.f*inner - xxj);       // reference formula order
  };
  int myj = topk20_reg(lane, getv);
  if (lane < 20) idx_out[(size_t)row*20 + lane] = myj;
}

// top-20 per row from a precomputed ord-dist matrix [4096][4096], no LDS
__global__ __launch_bounds__(256) void topk_rows(const unsigned* __restrict__ dg, int* __restrict__ idx_out){
  int tid = threadIdx.x, wv = tid >> 6, lane = tid & 63;
  int i = blockIdx.x * 4 + wv;
  const unsigned* drow = dg + (size_t)i * 4096;
  auto getv = [=](int s, int L)->unsigned{ return drow[s*64 + L]; };
  int myj = topk20_reg(lane, getv);
  if (lane < 20) idx_out[(size_t)i*20 + lane] = myj;
}

// ---------------------------------------------------------------------------
// Gram + negative-sq-distance (ord u32) for one batch: dg[i][j] = ord(2*G - xx_i - xx_j)
// x1 = xper rows (stride 128, first 64 cols). 128x128 block tile, 8x8 per lane.
// K staged in two 32-wide LDS chunks (32KB total).
__global__ __launch_bounds__(256) void gram_dist(const float* __restrict__ x1, const float* __restrict__ xx,
                                                 unsigned* __restrict__ dg){
  int it = blockIdx.y, jt = blockIdx.x;
  if (jt < it) return;                  // symmetry: mirror-write instead
  __shared__ __align__(16) float Atl[128*32];
  __shared__ __align__(16) float Btl[128*32];
  int tid = threadIdx.x;
  int wv = tid >> 6, lane = tid & 63;
  int wy = wv >> 1, wx = wv & 1, ly = lane >> 3, lx = lane & 7;
  int ib = wy*64 + ly*8, jb = wx*64 + lx*8;
  float acc[8][8] = {};
  for (int kc = 0; kc < 2; ++kc){
    __syncthreads();
    for (int q = 0; q < 4; ++q){
      int e4 = q*256 + tid;             // 1024 float4 per tile
      int r = e4 >> 3, c4 = e4 & 7;
      int cs = (c4 ^ ((r >> 3) & 7)) << 2;
      *(float4*)&Atl[r*32 + cs] = *(const float4*)&x1[(size_t)(it*128 + r)*128 + kc*32 + c4*4];
      *(float4*)&Btl[r*32 + cs] = *(const float4*)&x1[(size_t)(jt*128 + r)*128 + kc*32 + c4*4];
    }
    __syncthreads();
    for (int k4 = 0; k4 < 8; ++k4){
      float a[8][4], bb[8][4];
      #pragma unroll
      for (int p = 0; p < 8; ++p){
        float4 v = *(const float4*)&Atl[(ib + p)*32 + ((k4 ^ ly) << 2)];
        a[p][0]=v.x; a[p][1]=v.y; a[p][2]=v.z; a[p][3]=v.w;
        float4 u = *(const float4*)&Btl[(jb + p)*32 + ((k4 ^ lx) << 2)];
        bb[p][0]=u.x; bb[p][1]=u.y; bb[p][2]=u.z; bb[p][3]=u.w;
      }
      #pragma unroll
      for (int kk = 0; kk < 4; ++kk)
        #pragma unroll
        for (int p = 0; p < 8; ++p)
          #pragma unroll
          for (int q = 0; q < 8; ++q)
            acc[p][q] += a[p][kk] * bb[q][kk];
    }
  }
  float xxi[8], xxj[8];
  #pragma unroll
  for (int p = 0; p < 8; ++p){ xxi[p] = xx[it*128 + ib + p]; xxj[p] = xx[jt*128 + jb + p]; }
  #pragma unroll
  for (int p = 0; p < 8; ++p){
    unsigned ow[8];
    #pragma unroll
    for (int q = 0; q < 8; ++q){ float d = -xxi[p] + 2.f*acc[p][q] - xxj[q]; ow[q] = ordf(d); }
    size_t o = (size_t)(it*128 + ib + p)*4096 + jt*128 + jb;
    *(uint4*)&dg[o]   = make_uint4(ow[0],ow[1],ow[2],ow[3]);
    *(uint4*)&dg[o+4] = make_uint4(ow[4],ow[5],ow[6],ow[7]);
  }
  if (jt > it){
    #pragma unroll
    for (int q = 0; q < 8; ++q){
      unsigned ow[8];
      #pragma unroll
      for (int p = 0; p < 8; ++p){ float d = -xxi[p] + 2.f*acc[p][q] - xxj[q]; ow[p] = ordf(d); }
      size_t o = (size_t)(jt*128 + jb + q)*4096 + it*128 + ib;
      *(uint4*)&dg[o]   = make_uint4(ow[0],ow[1],ow[2],ow[3]);
      *(uint4*)&dg[o+4] = make_uint4(ow[4],ow[5],ow[6],ow[7]);
    }
  }
}

__global__ __launch_bounds__(256) void row_norms(const float* __restrict__ xper, float* __restrict__ xx){
  int wv = threadIdx.x >> 6, lane = threadIdx.x & 63;
  int row = blockIdx.x * 4 + wv;
  float v = xper[(size_t)row*128 + lane];   // x1 part (cols 0..63)
  float s = v*v;
  #pragma unroll
  for (int off = 32; off; off >>= 1) s += __shfl_xor(s, off);
  if (lane == 0) xx[row] = s;
}

// ---------------------------------------------------------------------------
// conv1a: z[row][o] = sum_c f(row)[c]*w1a[o][c], f = [xj-xi | xi], C=6.
// Also per-block channel partials of (z, z^2).
__global__ __launch_bounds__(256) void conv1a(const float* __restrict__ xyz, const int* __restrict__ idx,
                                              const float* __restrict__ w1a, float* __restrict__ out,
                                              float* __restrict__ part1, float* __restrict__ part2){
  int tid = threadIdx.x, wv = tid >> 6, lane = tid & 63;
  float w[6];
  #pragma unroll
  for (int c = 0; c < 6; ++c) w[c] = w1a[lane*6 + c];
  float s1 = 0.f, s2 = 0.f;
  int base = blockIdx.x*64 + wv*16;
  for (int r = 0; r < 16; ++r){
    int row = base + r;
    int bn = row / 20; int b = bn >> 12;
    int j = idx[row];
    const float* xb = xyz + (size_t)b * NN * 3;
    const float* xi = xb + (size_t)(bn & 4095) * 3;
    const float* xj = xb + (size_t)j * 3;
    float i0 = xi[0], i1 = xi[1], i2 = xi[2];
    float z = w[0]*(xj[0]-i0) + w[1]*(xj[1]-i1) + w[2]*(xj[2]-i2) + w[3]*i0 + w[4]*i1 + w[5]*i2;
    out[(size_t)row*64 + lane] = z;
    s1 += z; s2 += z*z;
  }
  __shared__ float red[2][4][64];
  red[0][wv][lane] = s1; red[1][wv][lane] = s2;
  __syncthreads();
  if (tid < 64)
    part1[(size_t)blockIdx.x*64 + tid] = red[0][0][tid]+red[0][1][tid]+red[0][2][tid]+red[0][3][tid];
  else if (tid < 128){
    int c = tid - 64;
    part2[(size_t)blockIdx.x*64 + c] = red[1][0][c]+red[1][1][c]+red[1][2][c]+red[1][3][c];
  }
}

// ---------------------------------------------------------------------------
// Generic rows-GEMM: out[row][o] = oscale * sum_c feat(row)[c] * W[o][c]
// VAR 0: feat = A rows (stride CIN).  VAR 1: feat = lrelu(bn(A rows)) via statsIn.
// VAR 2: feat = graph_feature gather from xper (CIN=128): [xj-xi | xi], j=idx[row].
// Block: 128 threads, 128 rows x 64 out-channels; per-lane 8x8 acc; k in chunks of 32.
// Optional per-block channel partials (z, z^2) for BN stats.
template<int CIN, int VAR>
__global__ __launch_bounds__(128) void gemm_rows(const float* A, const float* __restrict__ W,
                                                 float* out, int ostride,
                                                 float* __restrict__ part1, float* __restrict__ part2,
                                                 const float* __restrict__ statsIn,
                                                 const int* __restrict__ idx, float oscale){
  __shared__ __align__(16) float Al[128*32];
  __shared__ __align__(16) float Bl[64*32];
  __shared__ float pls[2][2][64];
  int tid = threadIdx.x;
  int wv = tid >> 6, lane = tid & 63;
  int ly = lane >> 3, lx = lane & 7;
  int rowbase = blockIdx.x * 128;
  int chb = blockIdx.y;
  float acc[8][8] = {};
  const int NKC = CIN / 32;
  for (int kc = 0; kc < NKC; ++kc){
    __syncthreads();
    // stage A: 128 rows x 32 k  (1024 float4, 8 per thread)
    for (int q8 = 0; q8 < 8; ++q8){
      int e4 = q8*128 + tid;
      int r = e4 >> 3, c4 = e4 & 7;
      int cg = kc*32 + c4*4;
      float4 v;
      if (VAR == 2){
        int row = rowbase + r;
        int bn = row / 20; int b = bn >> 12;
        int j = idx[row];
        const float* xi = A + (size_t)bn * 128;
        const float* xj = A + ((size_t)(b << 12) + j) * 128;
        if (cg < 64){
          float4 a1 = *(const float4*)&xj[cg];
          float4 a0 = *(const float4*)&xi[cg];
          v = make_float4(a1.x-a0.x, a1.y-a0.y, a1.z-a0.z, a1.w-a0.w);
        } else {
          v = *(const float4*)&xi[cg - 64];
        }
      } else {
        v = *(const float4*)&A[(size_t)(rowbase + r)*CIN + cg];
        if (VAR == 1){
          float4 m4 = *(const float4*)&statsIn[cg];
          float4 r4 = *(const float4*)&statsIn[CIN + cg];
          v.x = lrelu((v.x - m4.x)*r4.x); v.y = lrelu((v.y - m4.y)*r4.y);
          v.z = lrelu((v.z - m4.z)*r4.z); v.w = lrelu((v.w - m4.w)*r4.w);
        }
      }
      *(float4*)&Al[r*32 + ((c4 ^ ((r >> 3) & 7)) << 2)] = v;
    }
    // stage B: 64 ch x 32 k  (512 float4, 4 per thread)
    for (int q8 = 0; q8 < 4; ++q8){
      int e4 = q8*128 + tid;
      int ch = e4 >> 3, c4 = e4 & 7;
      float4 v = *(const float4*)&W[(size_t)(chb*64 + ch)*CIN + kc*32 + c4*4];
      *(float4*)&Bl[ch*32 + ((c4 ^ ((ch >> 3) & 7)) << 2)] = v;
    }
    __syncthreads();
    for (int k4 = 0; k4 < 8; ++k4){
      float a[8][4], bb[8][4];
      #pragma unroll
      for (int p = 0; p < 8; ++p){
        int r = wv*64 + ly*8 + p;                 // (r>>3)&7 == ly
        float4 v = *(const float4*)&Al[r*32 + ((k4 ^ ly) << 2)];
        a[p][0]=v.x; a[p][1]=v.y; a[p][2]=v.z; a[p][3]=v.w;
        int ch = lx*8 + p;                        // (ch>>3)&7 == lx
        float4 u = *(const float4*)&Bl[ch*32 + ((k4 ^ lx) << 2)];
        bb[p][0]=u.x; bb[p][1]=u.y; bb[p][2]=u.z; bb[p][3]=u.w;
      }
      #pragma unroll
      for (int kk = 0; kk < 4; ++kk)
        #pragma unroll
        for (int p = 0; p < 8; ++p)
          #pragma unroll
          for (int q = 0; q < 8; ++q)
            acc[p][q] += a[p][kk] * bb[q][kk];
    }
  }
  // write out (rows p, channels lx*8..lx*8+7)
  #pragma unroll
  for (int p = 0; p < 8; ++p){
    int row = rowbase + wv*64 + ly*8 + p;
    float4 o0 = make_float4(acc[p][0]*oscale, acc[p][1]*oscale, acc[p][2]*oscale, acc[p][3]*oscale);
    float4 o1 = make_float4(acc[p][4]*oscale, acc[p][5]*oscale, acc[p][6]*oscale, acc[p][7]*oscale);
    *(float4*)&out[(size_t)row*ostride + chb*64 + lx*8]     = o0;
    *(float4*)&out[(size_t)row*ostride + chb*64 + lx*8 + 4] = o1;
  }
  if (part1){
    // per-channel (z, z^2) partials: reduce over ly lanes via shuffles, then cross-wave via 1KB LDS
    #pragma unroll
    for (int q = 0; q < 8; ++q){
      float s1 = 0.f, s2 = 0.f;
      #pragma unroll
      for (int p = 0; p < 8; ++p){ float v = acc[p][q]; s1 += v; s2 += v*v; }
      #pragma unroll
      for (int off = 8; off < 64; off <<= 1){ s1 += __shfl_xor(s1, off); s2 += __shfl_xor(s2, off); }
      if (ly == 0){ pls[wv][0][lx*8 + q] = s1; pls[wv][1][lx*8 + q] = s2; }
    }
    __syncthreads();
    int nchTot = gridDim.y * 64;
    if (tid < 64)
      part1[(size_t)blockIdx.x*nchTot + chb*64 + tid] = pls[0][0][tid] + pls[1][0][tid];
    else if (tid < 128){
      int c = tid - 64;
      part2[(size_t)blockIdx.x*nchTot + chb*64 + c] = pls[0][1][c] + pls[1][1][c];
    }
  }
}

// deterministic partial -> (mean, rstd) per channel
__global__ __launch_bounds__(256) void stats_reduce(const float* __restrict__ p1, const float* __restrict__ p2,
                                                    float* __restrict__ statsOut, int nblk, int nch, float count){
  int ch = blockIdx.x, tid = threadIdx.x;
  float s1 = 0.f, s2 = 0.f;
  for (int i = tid; i < nblk; i += 256){ s1 += p1[(size_t)i*nch + ch]; s2 += p2[(size_t)i*nch + ch]; }
  __shared__ float r1[256], r2[256];
  r1[tid] = s1; r2[tid] = s2;
  __syncthreads();
  for (int off = 128; off; off >>= 1){
    if (tid < off){ r1[tid] += r1[tid+off]; r2[tid] += r2[tid+off]; }
    __syncthreads();
  }
  if (tid == 0){
    float m = r1[0] / count;
    float var = r2[0] / count - m*m;
    if (var < 0.f) var = 0.f;
    statsOut[ch] = m;
    statsOut[nch + ch] = rsqrtf(var + 1e-5f);
  }
}

// bn+lrelu then max over k=20 -> xper[:, off..off+63]
__global__ __launch_bounds__(256) void colmax(const float* __restrict__ buf, const float* __restrict__ st,
                                              float* __restrict__ xper, int off){
  int wv = threadIdx.x >> 6, lane = threadIdx.x & 63;
  int bn = blockIdx.x*4 + wv;
  float m = st[lane], rs = st[64 + lane];
  float mx = -INFINITY;
  for (int k = 0; k < 20; ++k){
    float z = buf[((size_t)bn*20 + k)*64 + lane];
    mx = fmaxf(mx, lrelu((z - m)*rs));
  }
  xper[(size_t)bn*128 + off + lane] = mx;
}

// bn+lrelu then max over n (atomicMax on ord-u32; order-independent => deterministic)
__global__ __launch_bounds__(256) void g_final(const float* __restrict__ z3, const float* __restrict__ st,
                                               unsigned* __restrict__ xglob){
  int t = threadIdx.x, zid = blockIdx.x;
  int b = zid >> 6, og = (zid >> 4) & 3, nc = zid & 15;
  int o = og*256 + t;
  float m = st[o], rs = st[1024 + o];
  float mx = -INFINITY;
  for (int r = 0; r < 256; ++r){
    float z = z3[((size_t)(b*4096 + nc*256 + r))*1024 + o];
    mx = fmaxf(mx, lrelu((z - m)*rs));
  }
  atomicMax(xglob + b*1024 + o, ordf(mx));
}

__global__ __launch_bounds__(256) void head(const unsigned* __restrict__ xglob,
                                            const float* __restrict__ mu_w, const float* __restrict__ mu_b,
                                            const float* __restrict__ var_w, const float* __restrict__ var_b,
                                            const float* __restrict__ eps_z, float* __restrict__ dout,
                                            float* __restrict__ zv){
  __shared__ __align__(16) float xg[1024];
  int b = blockIdx.x, t = threadIdx.x;
  for (int q = 0; q < 4; ++q) xg[q*256 + t] = iordf(xglob[b*1024 + q*256 + t]);
  __syncthreads();
  if (t < 128){
    float s1 = 0.f, s2 = 0.f;
    for (int c = 0; c < 1024; c += 4){
      float4 xv = *(const float4*)&xg[c];
      float4 wa = *(const float4*)&mu_w[(size_t)t*1024 + c];
      float4 wb = *(const float4*)&var_w[(size_t)t*1024 + c];
      s1 += wa.x*xv.x + wa.y*xv.y + wa.z*xv.z + wa.w*xv.w;
      s2 += wb.x*xv.x + wb.y*xv.y + wb.z*xv.z + wb.w*xv.w;
    }
    float mu = s1 + mu_b[t];
    float lv = s2 + var_b[t];
    dout[458816 + b*128 + t] = mu;
    dout[459328 + b*128 + t] = lv;
    zv[b*128 + t] = eps_z[b*128 + t] * expf(0.5f*lv) + mu;
  }
}

// cuboid MLP + Para_pred per (b,m): xc(192) -> h1(256) -> x_cuboid(128) -> {Km, quat->rot, trans, exist}
__global__ __launch_bounds__(256) void cuboid(const float* __restrict__ zv, const float* __restrict__ enc_w,
                                              const float* __restrict__ w1, const float* __restrict__ w2,
                                              const float* __restrict__ rot_w, const float* __restrict__ rot_b,
                                              const float* __restrict__ trans_w, const float* __restrict__ trans_b,
                                              const float* __restrict__ ext_w1, const float* __restrict__ ext_b1,
                                              const float* __restrict__ ext_w2, const float* __restrict__ ext_b2,
                                              const float* __restrict__ k_w, float* __restrict__ Km,
                                              float* __restrict__ rot, float* __restrict__ trs,
                                              float* __restrict__ dout){
  int bm = blockIdx.x; int b = bm >> 4, m = bm & 15; int t = threadIdx.x;
  __shared__ __align__(16) float xc[192];
  __shared__ __align__(16) float h1[256];
  __shared__ __align__(16) float xcu[128];
  __shared__ float qv[4]; __shared__ float ev[30];
  if (t < 192) xc[t] = (t < 128) ? zv[b*128 + t] : lrelu(enc_w[(t-128)*16 + m]);
  __syncthreads();
  {
    float s = 0.f; const float* wr = w1 + (size_t)t*192;
    for (int c = 0; c < 192; c += 4){
      float4 w4 = *(const float4*)&wr[c]; float4 x4 = *(const float4*)&xc[c];
      s += w4.x*x4.x + w4.y*x4.y + w4.z*x4.z + w4.w*x4.w;
    }
    h1[t] = lrelu(s);
  }
  __syncthreads();
  if (t < 128){
    float s = 0.f; const float* wr = w2 + (size_t)t*256;
    for (int c = 0; c < 256; c += 4){
      float4 w4 = *(const float4*)&wr[c]; float4 x4 = *(const float4*)&h1[c];
      s += w4.x*x4.x + w4.y*x4.y + w4.z*x4.z + w4.w*x4.w;
    }
    xcu[t] = lrelu(s);
  }
  __syncthreads();
  if (t < 64){
    float s = 0.f;
    for (int c = 0; c < 128; ++c) s += xcu[c]*k_w[(size_t)t*128 + c];
    Km[(size_t)(b*16 + m)*64 + t] = s;
  } else if (t < 68){
    int o = t - 64; float s = rot_b[o];
    for (int c = 0; c < 128; ++c) s += xcu[c]*rot_w[(size_t)o*128 + c];
    qv[o] = s;
  } else if (t < 71){
    int o = t - 68; float s = trans_b[o];
    for (int c = 0; c < 128; ++c) s += xcu[c]*trans_w[(size_t)o*128 + c];
    trs[(size_t)(b*16 + m)*3 + o] = tanhf(s);
  } else if (t < 101){
    int o = t - 71; float s = ext_b1[o];
    for (int c = 0; c < 128; ++c) s += xcu[c]*ext_w1[(size_t)o*128 + c];
    ev[o] = lrelu(s);
  }
  __syncthreads();
  if (t == 0){
    float w = qv[0], x = qv[1], y = qv[2], z = qv[3];
    float nrm = sqrtf(w*w + x*x + y*y + z*z);
    float inv = 1.f / fmaxf(nrm, 1e-12f);
    w *= inv; x *= inv; y *= inv; z *= inv;
    float xx2 = x*x, yy = y*y, zz = z*z;
    float* r = rot + (size_t)(b*16 + m)*9;
    r[0] = 1.f - 2.f*(yy + zz); r[1] = 2.f*(x*y - w*z); r[2] = 2.f*(x*z + w*y);
    r[3] = 2.f*(x*y + w*z); r[4] = 1.f - 2.f*(xx2 + zz); r[5] = 2.f*(y*z - w*x);
    r[6] = 2.f*(x*z - w*y); r[7] = 2.f*(y*z + w*x); r[8] = 1.f - 2.f*(xx2 + yy);
  }
  if (t == 1){
    float s = ext_b2[0];
    for (int o = 0; o < 30; ++o) s += ev[o]*ext_w2[o];
    dout[458752 + b*16 + m] = s;
  }
}

// attention epilogue: scores, softmax over m, assign / assign_rotate / assign_trans
__global__ __launch_bounds__(256) void attn(const float* __restrict__ Qbuf, const float* __restrict__ Km,
                                            const float* __restrict__ rot, const float* __restrict__ trs,
                                            float* __restrict__ dout){
  __shared__ float kml[16*64];
  __shared__ float rl[144], tl[48];
  __shared__ float Ql[4][64];
  __shared__ float al[4][16];
  int tid = threadIdx.x, wv = tid >> 6, lane = tid & 63;
  int bn0 = blockIdx.x*4; int b = bn0 >> 12;
  for (int e = tid; e < 1024; e += 256){
    int m = e >> 6, d = e & 63;
    kml[m*64 + (d ^ ((m & 15) << 2))] = Km[(size_t)b*1024 + e];
  }
  if (tid < 144) rl[tid] = rot[(size_t)b*144 + tid];
  if (tid < 48)  tl[tid] = trs[(size_t)b*48 + tid];
  __syncthreads();
  int bn = bn0 + wv;
  Ql[wv][lane] = Qbuf[(size_t)bn*64 + lane];
  if (lane < 16){
    float sc = 0.f;
    for (int d = 0; d < 64; ++d) sc += Ql[wv][d] * kml[lane*64 + (d ^ ((lane & 15) << 2))];
    float mx = sc;
    #pragma unroll
    for (int off = 8; off; off >>= 1) mx = fmaxf(mx, __shfl_xor(mx, off));
    float e = expf(sc - mx);
    float sm = e;
    #pragma unroll
    for (int off = 8; off; off >>= 1) sm += __shfl_xor(sm, off);
    float a = e / sm;
    dout[(size_t)bn*16 + lane] = a;           // assign
    al[wv][lane] = a;
  }
  if (lane < 9){
    float s = 0.f;
    for (int m = 0; m < 16; ++m) s += al[wv][m] * rl[m*9 + lane];
    dout[262144 + (size_t)bn*9 + lane] = s;   // assign_rotate
  }
  if (lane >= 16 && lane < 19){
    int d = lane - 16;
    float s = 0.f;
    for (int m = 0; m < 16; ++m) s += al[wv][m] * tl[m*3 + d];
    dout[409600 + (size_t)bn*3 + d] = s;      // assign_trans
  }
}

// ---------------------------------------------------------------------------
extern "C" void kernel_launch(void* const* d_in, const int* in_sizes, int n_in,
                              void* d_out, int out_size, void* d_ws, size_t ws_size,
                              hipStream_t stream){
  (void)in_sizes; (void)n_in; (void)out_size; (void)ws_size;
  const float* xyz     = (const float*)d_in[0];
  const float* eps_z   = (const float*)d_in[2];
  const float* w1a     = (const float*)d_in[3];
  const float* w1b     = (const float*)d_in[4];
  const float* w2a     = (const float*)d_in[5];
  const float* w2b     = (const float*)d_in[6];
  const float* w3      = (const float*)d_in[7];
  const float* mu_w    = (const float*)d_in[8];
  const float* mu_b    = (const float*)d_in[9];
  const float* var_w   = (const float*)d_in[10];
  const float* var_b   = (const float*)d_in[11];
  const float* enc_w   = (const float*)d_in[12];
  const float* cw1     = (const float*)d_in[13];
  const float* cw2     = (const float*)d_in[14];
  const float* q_w     = (const float*)d_in[15];
  const float* k_w     = (const float*)d_in[16];
  const float* rot_w   = (const float*)d_in[19];
  const float* rot_b   = (const float*)d_in[20];
  const float* trans_w = (const float*)d_in[21];
  const float* trans_b = (const float*)d_in[22];
  const float* ext_w1  = (const float*)d_in[23];
  const float* ext_b1  = (const float*)d_in[24];
  const float* ext_w2  = (const float*)d_in[25];
  const float* ext_b2  = (const float*)d_in[26];
  float* dout = (float*)d_out;

  char* wsb = (char*)d_ws;
  size_t off = 0;
  float* buf   = (float*)(wsb + off); off += 83886080;      // [B,N,K,64] f32; reused for dist (64MB) and z3 (64MB)
  int*   idx0  = (int*)(wsb + off);   off += 1310720;
  int*   idx1  = (int*)(wsb + off);   off += 1310720;
  float* xper  = (float*)(wsb + off); off += 8388608;       // [B,N,128] = [x1|x2]
  float* xx    = (float*)(wsb + off); off += 65536;
  float* part1 = (float*)(wsb + off); off += 4194304;       // 1M floats; reused as Qbuf
  float* part2 = (float*)(wsb + off); off += 4194304;
  float* st1a  = (float*)(wsb + off); off += 512;
  float* st1b  = (float*)(wsb + off); off += 512;
  float* st2a  = (float*)(wsb + off); off += 512;
  float* st2b  = (float*)(wsb + off); off += 512;
  float* st3   = (float*)(wsb + off); off += 8192;
  unsigned* xglob = (unsigned*)(wsb + off); off += 16384;
  float* zv    = (float*)(wsb + off); off += 2048;
  float* Kmb   = (float*)(wsb + off); off += 16384;
  float* rotb  = (float*)(wsb + off); off += 2304;
  float* trsb  = (float*)(wsb + off); off += 768;

  // --- Feature_extract, block 1 ---
  knn_xyz<<<4096, 256, 0, stream>>>(xyz, idx0);
  conv1a<<<5120, 256, 0, stream>>>(xyz, idx0, w1a, buf, part1, part2);
  stats_reduce<<<64, 256, 0, stream>>>(part1, part2, st1a, 5120, 64, 327680.f);
  gemm_rows<64,1><<<dim3(2560,1), 128, 0, stream>>>(buf, w1b, buf, 64, part1, part2, st1a, nullptr, 1.f);
  stats_reduce<<<64, 256, 0, stream>>>(part1, part2, st1b, 2560, 64, 327680.f);
  colmax<<<4096, 256, 0, stream>>>(buf, st1b, xper, 0);     // x1

  // --- knn on x1 (Gram -> ord-dist -> topk), per batch, dist reuses buf ---
  row_norms<<<4096, 256, 0, stream>>>(xper, xx);
  for (int b = 0; b < 4; ++b){
    gram_dist<<<dim3(32,32), 256, 0, stream>>>(xper + (size_t)b*NN*128, xx + (size_t)b*NN, (unsigned*)buf);
    topk_rows<<<1024, 256, 0, stream>>>((unsigned*)buf, idx1 + (size_t)b*NN*KK);
  }

  // --- Feature_extract, block 2 ---
  gemm_rows<128,2><<<dim3(2560,1), 128, 0, stream>>>(xper, w2a, buf, 64, part1, part2, nullptr, idx1, 1.f);
  stats_reduce<<<64, 256, 0, stream>>>(part1, part2, st2a, 2560, 64, 327680.f);
  gemm_rows<64,1><<<dim3(2560,1), 128, 0, stream>>>(buf, w2b, buf, 64, part1, part2, st2a, nullptr, 1.f);
  stats_reduce<<<64, 256, 0, stream>>>(part1, part2, st2b, 2560, 64, 327680.f);
  colmax<<<4096, 256, 0, stream>>>(buf, st2b, xper, 64);    // x2

  // --- global embedding g = lrelu(bn(xper @ w3^T)), x_global = max_n ---
  gemm_rows<128,0><<<dim3(128,16), 128, 0, stream>>>(xper, w3, buf, 1024, part1, part2, nullptr, nullptr, 1.f);
  stats_reduce<<<1024, 256, 0, stream>>>(part1, part2, st3, 128, 1024, 16384.f);
  hipMemsetAsync(xglob, 0, 4096*sizeof(unsigned), stream);  // ord-space minimum
  g_final<<<256, 256, 0, stream>>>(buf, st3, xglob);

  // --- heads ---
  head<<<4, 256, 0, stream>>>(xglob, mu_w, mu_b, var_w, var_b, eps_z, dout, zv);
  cuboid<<<64, 256, 0, stream>>>(zv, enc_w, cw1, cw2, rot_w, rot_b, trans_w, trans_b,
                                 ext_w1, ext_b1, ext_w2, ext_b2, k_w, Kmb, rotb, trsb, dout);
  gemm_rows<128,0><<<dim3(128,1), 128, 0, stream>>>(xper, q_w, part1, 64, nullptr, nullptr, nullptr, nullptr, 0.125f);
  attn<<<4096, 256, 0, stream>>>(part1, Kmb, rotb, trsb, dout);
}